// Round 1
// baseline (3214.450 us; speedup 1.0000x reference)
//
#include <hip/hip_runtime.h>
#include <math.h>

#define T_LEN 16000
#define NTILE 250          // time tiles per batch row (16000/64)
#define TT 64              // time tile
#define NBLK 2000          // 8 * 250

static const int N_RES = 8 * 32 * T_LEN;   // 4,096,000 floats per residual buffer

// ---------------- weight repack: transpose for coalesced lane reads ----------------
__global__ __launch_bounds__(256) void repack_k(
    const float* __restrict__ Wd, const float* __restrict__ Wr,
    const float* __restrict__ Ws, const float* __restrict__ We1,
    const float* __restrict__ We2,
    float* __restrict__ WdR, float* __restrict__ WrT, float* __restrict__ WsT,
    float* __restrict__ We1T, float* __restrict__ We2T) {
  int i = blockIdx.x * 256 + threadIdx.x;
  // WdR[l][k][c][o] <- Wd[l][o][c][k]   (40*2*32*128 = 327680)
  if (i < 40 * 8192) {
    int l = i >> 13, r = i & 8191;
    int k = r >> 12, c = (r >> 7) & 31, o = r & 127;
    WdR[i] = Wd[(((l * 128 + o) * 32 + c) << 1) + k];
  }
  // WrT[l][o][o2] <- Wr[l][o2][o]       (40*128*32 = 163840)
  if (i < 40 * 4096) {
    int l = i >> 12, r = i & 4095;
    int o = r >> 5, o2 = r & 31;
    WrT[i] = Wr[(l * 32 + o2) * 128 + o];
  }
  // WsT[c][o] <- Ws[o][c]               (256*32)
  if (i < 8192) {
    int c = i >> 5, o = i & 31;
    WsT[i] = Ws[o * 256 + c];
  }
  // We1T[c][o] <- We1[o][c]             (32*256)
  if (i < 8192) {
    int c = i >> 8, o = i & 255;
    We1T[i] = We1[o * 32 + c];
  }
  // We2T[c][o] <- We2[o][c]             (256*256)
  if (i < 65536) {
    int c = i >> 8, o = i & 255;
    We2T[i] = We2[o * 256 + c];
  }
}

// ---------------- start 1x1 conv: residual = W_start @ x ----------------
__global__ __launch_bounds__(256) void start_k(const float* __restrict__ x,
                                               const float* __restrict__ WsT,
                                               float* __restrict__ res) {
  __shared__ float xs[32][68];
  int b = blockIdx.x / NTILE;
  int t0 = (blockIdx.x % NTILE) * TT;
  int tid = threadIdx.x;
  int o = tid & 31, tg = (tid >> 5) * 8;       // 32 out-ch x 8 t-groups
  int lr = tid >> 3, lt = (tid & 7) * 8;       // staging map
  float acc[8];
#pragma unroll
  for (int j = 0; j < 8; ++j) acc[j] = 0.f;
  for (int cc = 0; cc < 8; ++cc) {
    __syncthreads();
    const float* xp = x + ((size_t)b * 256 + cc * 32 + lr) * T_LEN + t0 + lt;
    *(float4*)&xs[lr][lt]     = *(const float4*)xp;
    *(float4*)&xs[lr][lt + 4] = *(const float4*)(xp + 4);
    __syncthreads();
#pragma unroll 4
    for (int c = 0; c < 32; ++c) {
      float w = WsT[(cc * 32 + c) * 32 + o];
      const float* xr = &xs[c][tg];
#pragma unroll
      for (int j = 0; j < 8; ++j) acc[j] += w * xr[j];
    }
  }
  float* rp = res + ((size_t)b * 32 + o) * T_LEN + t0 + tg;
  *(float4*)rp       = make_float4(acc[0], acc[1], acc[2], acc[3]);
  *(float4*)(rp + 4) = make_float4(acc[4], acc[5], acc[6], acc[7]);
}

// ---------------- fused WaveNet layer: dilated conv + gate + 1x1 + residual/skip ----------------
__global__ __launch_bounds__(256) void layer_k(const float* __restrict__ resIn,
                                               float* __restrict__ resOut,
                                               float* __restrict__ skips,
                                               const float* __restrict__ WdL,
                                               const float* __restrict__ WrL, int d) {
  __shared__ float cur[32][68];   // res_in at t        (also reused for residual add)
  __shared__ float prv[32][68];   // res_in at t-d      (reused as skip staging)
  __shared__ float g[128][68];    // gated activations
  int b = blockIdx.x / NTILE;
  int t0 = (blockIdx.x % NTILE) * TT;
  int tid = threadIdx.x;
  int lr = tid >> 3, lt = (tid & 7) * 8;

  const float* rip = resIn + ((size_t)b * 32 + lr) * T_LEN;
  *(float4*)&cur[lr][lt]     = *(const float4*)(rip + t0 + lt);
  *(float4*)&cur[lr][lt + 4] = *(const float4*)(rip + t0 + lt + 4);
  {
    float p[8];
#pragma unroll
    for (int j = 0; j < 8; ++j) {
      int tp = t0 + lt + j - d;
      p[j] = (tp >= 0) ? rip[tp] : 0.f;
    }
    *(float4*)&prv[lr][lt]     = make_float4(p[0], p[1], p[2], p[3]);
    *(float4*)&prv[lr][lt + 4] = make_float4(p[4], p[5], p[6], p[7]);
  }
  __syncthreads();

  // phase A: h = Wd0 @ res[t-d] + Wd1 @ res[t]; g = tanh(h)*sigmoid(h)
  {
    int o = tid & 127, half = (tid >> 7) * 32;
    float h[32];
#pragma unroll
    for (int t = 0; t < 32; ++t) h[t] = 0.f;
    const float* w0p = WdL + o;
    const float* w1p = WdL + 4096 + o;
    for (int c = 0; c < 32; ++c) {
      float w0 = w0p[c * 128];
      float w1 = w1p[c * 128];
      const float* p = &prv[c][half];
      const float* q = &cur[c][half];
#pragma unroll
      for (int t = 0; t < 32; ++t) h[t] += w0 * p[t] + w1 * q[t];
    }
#pragma unroll
    for (int t = 0; t < 32; ++t) {
      // tanh(v)*sigmoid(v) == (1-e)/(1+e*e) with e = exp(-v)
      float v = fmaxf(h[t], -40.f);
      float e = __expf(-v);
      h[t] = (1.f - e) / (1.f + e * e);
    }
#pragma unroll
    for (int t = 0; t < 32; t += 4)
      *(float4*)&g[o][half + t] = make_float4(h[t], h[t + 1], h[t + 2], h[t + 3]);
  }
  __syncthreads();

  // phase B: skip = Wres @ g
  {
    int o2 = tid & 31, tg = (tid >> 5) * 8;
    float s[8];
#pragma unroll
    for (int j = 0; j < 8; ++j) s[j] = 0.f;
    const float* wp = WrL + o2;
    for (int oo = 0; oo < 128; ++oo) {
      float w = wp[oo * 32];
      const float* gr = &g[oo][tg];
#pragma unroll
      for (int j = 0; j < 8; ++j) s[j] += w * gr[j];
    }
#pragma unroll
    for (int j = 0; j < 8; j += 4)
      *(float4*)&prv[o2][tg + j] = make_float4(s[j], s[j + 1], s[j + 2], s[j + 3]);
  }
  __syncthreads();

  // writeout: resOut = resIn + skip ; skips += skip   (coalesced remap)
  {
    size_t base = ((size_t)b * 32 + lr) * T_LEN + t0 + lt;
    float* rop = resOut + base;
    float* skp = skips + base;
#pragma unroll
    for (int v = 0; v < 8; v += 4) {
      float4 sv = *(float4*)&prv[lr][lt + v];
      float4 cv = *(float4*)&cur[lr][lt + v];
      float4 so = *(const float4*)(skp + v);
      float4 ro;
      ro.x = cv.x + sv.x; ro.y = cv.y + sv.y; ro.z = cv.z + sv.z; ro.w = cv.w + sv.w;
      *(float4*)(rop + v) = ro;
      float4 sn;
      sn.x = so.x + sv.x; sn.y = so.y + sv.y; sn.z = so.z + sv.z; sn.w = so.w + sv.w;
      *(float4*)(skp + v) = sn;
    }
  }
}

// ---------------- end: relu(skips) -> relu(We1 @ .) -> We2 @ . ----------------
__global__ __launch_bounds__(256) void end_k(const float* __restrict__ skips,
                                             const float* __restrict__ We1T,
                                             const float* __restrict__ We2T,
                                             float* __restrict__ out) {
  __shared__ float h1[32][68];
  __shared__ float h2[256][68];
  int b = blockIdx.x / NTILE;
  int t0 = (blockIdx.x % NTILE) * TT;
  int tid = threadIdx.x;
  int lr = tid >> 3, lt = (tid & 7) * 8;
  {
    const float* sp = skips + ((size_t)b * 32 + lr) * T_LEN + t0 + lt;
    float4 v0 = *(const float4*)sp;
    float4 v1 = *(const float4*)(sp + 4);
    v0.x = fmaxf(v0.x, 0.f); v0.y = fmaxf(v0.y, 0.f); v0.z = fmaxf(v0.z, 0.f); v0.w = fmaxf(v0.w, 0.f);
    v1.x = fmaxf(v1.x, 0.f); v1.y = fmaxf(v1.y, 0.f); v1.z = fmaxf(v1.z, 0.f); v1.w = fmaxf(v1.w, 0.f);
    *(float4*)&h1[lr][lt]     = v0;
    *(float4*)&h1[lr][lt + 4] = v1;
  }
  __syncthreads();
  int og = tid & 63, tg = (tid >> 6) * 16;   // o = jj*64+og (row-interleaved), 16 t
  float acc[4][16];
#pragma unroll
  for (int jj = 0; jj < 4; ++jj)
#pragma unroll
    for (int t = 0; t < 16; ++t) acc[jj][t] = 0.f;
  for (int c = 0; c < 32; ++c) {
    float w[4];
#pragma unroll
    for (int jj = 0; jj < 4; ++jj) w[jj] = We1T[c * 256 + jj * 64 + og];
    const float* hr = &h1[c][tg];
#pragma unroll
    for (int t = 0; t < 16; ++t) {
      float xv = hr[t];
#pragma unroll
      for (int jj = 0; jj < 4; ++jj) acc[jj][t] += w[jj] * xv;
    }
  }
#pragma unroll
  for (int jj = 0; jj < 4; ++jj)
#pragma unroll
    for (int t = 0; t < 16; t += 4)
      *(float4*)&h2[jj * 64 + og][tg + t] =
          make_float4(fmaxf(acc[jj][t], 0.f), fmaxf(acc[jj][t + 1], 0.f),
                      fmaxf(acc[jj][t + 2], 0.f), fmaxf(acc[jj][t + 3], 0.f));
  __syncthreads();
  float a2[4][16];
#pragma unroll
  for (int jj = 0; jj < 4; ++jj)
#pragma unroll
    for (int t = 0; t < 16; ++t) a2[jj][t] = 0.f;
  for (int c = 0; c < 256; ++c) {
    float w[4];
#pragma unroll
    for (int jj = 0; jj < 4; ++jj) w[jj] = We2T[c * 256 + jj * 64 + og];
    const float* hr = &h2[c][tg];
#pragma unroll
    for (int t = 0; t < 16; ++t) {
      float xv = hr[t];
#pragma unroll
      for (int jj = 0; jj < 4; ++jj) a2[jj][t] += w[jj] * xv;
    }
  }
#pragma unroll
  for (int jj = 0; jj < 4; ++jj) {
    float* op = out + ((size_t)b * 256 + jj * 64 + og) * T_LEN + t0 + tg;
#pragma unroll
    for (int t = 0; t < 16; t += 4)
      *(float4*)(op + t) =
          make_float4(a2[jj][t], a2[jj][t + 1], a2[jj][t + 2], a2[jj][t + 3]);
  }
}

extern "C" void kernel_launch(void* const* d_in, const int* in_sizes, int n_in,
                              void* d_out, int out_size, void* d_ws, size_t ws_size,
                              hipStream_t stream) {
  const float* x   = (const float*)d_in[0];
  const float* Wst = (const float*)d_in[1];
  const float* Wd  = (const float*)d_in[2];
  const float* Wr  = (const float*)d_in[3];
  const float* We1 = (const float*)d_in[4];
  const float* We2 = (const float*)d_in[5];
  float* out = (float*)d_out;
  float* ws = (float*)d_ws;

  float* resA  = ws;
  float* resB  = resA + N_RES;
  float* skips = resB + N_RES;
  float* WdR   = skips + N_RES;        // 40*8192
  float* WrT   = WdR + 40 * 8192;      // 40*4096
  float* WsT   = WrT + 40 * 4096;      // 8192
  float* We1T  = WsT + 8192;           // 8192
  float* We2T  = We1T + 8192;          // 65536

  hipMemsetAsync(skips, 0, (size_t)N_RES * sizeof(float), stream);
  repack_k<<<1280, 256, 0, stream>>>(Wd, Wr, Wst, We1, We2, WdR, WrT, WsT, We1T, We2T);
  start_k<<<NBLK, 256, 0, stream>>>(x, WsT, resA);

  const float* rin = resA;
  float* rout = resB;
  for (int l = 0; l < 40; ++l) {
    layer_k<<<NBLK, 256, 0, stream>>>(rin, rout, skips,
                                      WdR + l * 8192, WrT + l * 4096, 1 << (l % 10));
    const float* tmp = rout;
    rout = (float*)rin;
    rin = tmp;
  }
  end_k<<<NBLK, 256, 0, stream>>>(skips, We1T, We2T, out);
}

// Round 2
// 1651.886 us; speedup vs baseline: 1.9459x; 1.9459x over previous
//
#include <hip/hip_runtime.h>
#include <math.h>

#define T_LEN 16000
#define NTILE 250          // time tiles per batch row (16000/64)
#define TT 64              // time tile
#define NBLK 2000          // 8 * 250

static const int N_RES = 8 * 32 * T_LEN;   // 4,096,000 floats per residual buffer

typedef _Float16 half_t;
typedef __attribute__((ext_vector_type(8))) _Float16 halfx8;
typedef __attribute__((ext_vector_type(4))) _Float16 halfx4;
typedef __attribute__((ext_vector_type(16))) float f32x16;

#define MFMA(a, b, c) __builtin_amdgcn_mfma_f32_32x32x16_f16((a), (b), (c), 0, 0, 0)

// ---------------- weight repack ----------------
// WaG[l][o=0..127][c=0..127] fp16: c<64 = hi split of Wbase[o][c] (Wbase[o][c]=Wd[l][o][c&31][c>>5]),
//                                  c>=64 = (Wbase - hi)*2048 (lo split, pre-scaled)
// WrG[l][o2=0..31][c=0..255] fp16: c<128 = hi of Wr[l][c][o2]^T ... (row o2, col c = in-channel), c>=128 lo*2048
__global__ __launch_bounds__(256) void repack_k(
    const float* __restrict__ Wd, const float* __restrict__ Wr,
    const float* __restrict__ Ws, const float* __restrict__ We1,
    const float* __restrict__ We2,
    half_t* __restrict__ WaG, half_t* __restrict__ WrG, float* __restrict__ WsT,
    float* __restrict__ We1T, float* __restrict__ We2T) {
  int i = blockIdx.x * 256 + threadIdx.x;
  if (i < 40 * 128 * 128) {
    int l = i >> 14, r = i & 16383, o = r >> 7, c = r & 127;
    int cb = c & 63, chan = cb & 31, tap = cb >> 5;
    float w = Wd[(((l * 128 + o) * 32 + chan) << 1) + tap];
    half_t w0 = (half_t)w;
    WaG[i] = (c < 64) ? w0 : (half_t)((w - (float)w0) * 2048.f);
  }
  if (i < 40 * 32 * 256) {
    int l = i >> 13, r = i & 8191, o = r >> 8, c = r & 255;
    int cb = c & 127;
    float w = Wr[(l * 32 + o) * 128 + cb];
    half_t w0 = (half_t)w;
    WrG[i] = (c < 128) ? w0 : (half_t)((w - (float)w0) * 2048.f);
  }
  // WsT[c][o] <- Ws[o][c]  (256x32)
  if (i < 8192) {
    int c = i >> 5, o = i & 31;
    WsT[i] = Ws[o * 256 + c];
  }
  // We1T[c][o] <- We1[o][c] (32x256)
  if (i < 8192) {
    int c = i >> 8, o = i & 255;
    We1T[i] = We1[o * 32 + c];
  }
  // We2T[c][o] <- We2[o][c] (256x256)
  if (i < 65536) {
    int c = i >> 8, o = i & 255;
    We2T[i] = We2[o * 256 + c];
  }
}

// ---------------- start 1x1 conv (f32): residual = W_start @ x ----------------
__global__ __launch_bounds__(256) void start_k(const float* __restrict__ x,
                                               const float* __restrict__ WsT,
                                               float* __restrict__ res) {
  __shared__ float xs[32][68];
  int b = blockIdx.x / NTILE;
  int t0 = (blockIdx.x % NTILE) * TT;
  int tid = threadIdx.x;
  int o = tid & 31, tg = (tid >> 5) * 8;
  int lr = tid >> 3, lt = (tid & 7) * 8;
  float acc[8];
#pragma unroll
  for (int j = 0; j < 8; ++j) acc[j] = 0.f;
  for (int cc = 0; cc < 8; ++cc) {
    __syncthreads();
    const float* xp = x + ((size_t)b * 256 + cc * 32 + lr) * T_LEN + t0 + lt;
    *(float4*)&xs[lr][lt]     = *(const float4*)xp;
    *(float4*)&xs[lr][lt + 4] = *(const float4*)(xp + 4);
    __syncthreads();
#pragma unroll 4
    for (int c = 0; c < 32; ++c) {
      float w = WsT[(cc * 32 + c) * 32 + o];
      const float* xr = &xs[c][tg];
#pragma unroll
      for (int j = 0; j < 8; ++j) acc[j] += w * xr[j];
    }
  }
  float* rp = res + ((size_t)b * 32 + o) * T_LEN + t0 + tg;
  *(float4*)rp       = make_float4(acc[0], acc[1], acc[2], acc[3]);
  *(float4*)(rp + 4) = make_float4(acc[4], acc[5], acc[6], acc[7]);
}

// ---------------- fused WaveNet layer: MFMA fp16 split-2 ----------------
// LDS map (bytes), aliased by phase:
//   [0     .. 34816)  Wa   128 rows x 272B (K=128 fp16 + 8 pad)     | phase B: gT 64 rows x 528B (33792)
//   [34816 .. 52224)  zT    64 rows x 272B                          | phase C: skb 2 x 32 x 68 f32
//   [52224 .. 69120)  Wr2   32 rows x 528B (K=256 fp16 + 8 pad)
__global__ __launch_bounds__(256) void layer_k(const float* __restrict__ resIn,
                                               float* __restrict__ resOut,
                                               const half_t* __restrict__ WaL,
                                               const half_t* __restrict__ WrL, int d) {
  __shared__ __align__(16) char sm[69120];
  const int WA_OFF = 0, ZT_OFF = 34816, WR_OFF = 52224, GT_OFF = 0, SKB_OFF = 34816;
  int tid = threadIdx.x;
  int b = blockIdx.x / NTILE;
  int t0 = (blockIdx.x % NTILE) * TT;

  // ---- stage Wa (32KB) ----
  {
    int row = tid >> 1, hf = tid & 1;
    const float4* src = (const float4*)(WaL + row * 128 + hf * 64);
    char* dst = sm + WA_OFF + row * 272 + hf * 128;
#pragma unroll
    for (int j = 0; j < 8; ++j) *(float4*)(dst + j * 16) = src[j];
  }
  // ---- stage Wr2 (16KB) ----
  {
    int row = tid >> 3, chunk = tid & 7;
    const float4* src = (const float4*)(WrL + row * 256 + chunk * 32);
    char* dst = sm + WR_OFF + row * 528 + chunk * 64;
#pragma unroll
    for (int j = 0; j < 4; ++j) *(float4*)(dst + j * 16) = src[j];
  }
  // ---- stage zT: rows(K): 0..31 prv-hi, 32..63 cur-hi, 64..95 prv-lo*2048, 96..127 cur-lo*2048 ----
  {
    int c = tid >> 3, tt = (tid & 7) * 8;
    const float* rip = resIn + ((size_t)b * 32 + c) * T_LEN;
    float cv[8], pv[8];
    *(float4*)cv       = *(const float4*)(rip + t0 + tt);
    *(float4*)(cv + 4) = *(const float4*)(rip + t0 + tt + 4);
#pragma unroll
    for (int j = 0; j < 8; ++j) {
      int tp = t0 + tt + j - d;
      pv[j] = (tp >= 0) ? rip[tp] : 0.f;
    }
#pragma unroll
    for (int j = 0; j < 8; ++j) {
      half_t* zrow = (half_t*)(sm + ZT_OFF + (tt + j) * 272);
      half_t p0 = (half_t)pv[j];
      half_t p1 = (half_t)((pv[j] - (float)p0) * 2048.f);
      half_t c0 = (half_t)cv[j];
      half_t c1 = (half_t)((cv[j] - (float)c0) * 2048.f);
      zrow[c]      = p0;
      zrow[c + 32] = c0;
      zrow[c + 64] = p1;
      zrow[c + 96] = c1;
    }
  }
  __syncthreads();

  int wave = tid >> 6, lane = tid & 63;
  int l31 = lane & 31, lhi = lane >> 5;

  // ---- GEMM1: h[128,64] = W @ z, K=192 effective (12 K-steps of 16) ----
  halfx4 t0h[4], t0l[4], t1h[4], t1l[4];   // packed gate splits per output tile
  {
    int mh = wave & 1, nh = wave >> 1;
    int colt = nh * 32 + l31;
    const char* zrow  = sm + ZT_OFF + colt * 272 + lhi * 16;
    const char* arow0 = sm + WA_OFF + (mh * 64 + l31) * 272 + lhi * 16;
    const char* arow1 = arow0 + 32 * 272;
    f32x16 hi0{}, hi1{}, lo0{}, lo1{};
#pragma unroll
    for (int ks = 0; ks < 12; ++ks) {
      int acol = (ks < 8) ? (ks & 3) * 16 : (ks & 3) * 16 + 64;
      int brow = (ks < 4) ? ks * 16 : ((ks < 8) ? (ks & 3) * 16 + 64 : (ks & 3) * 16);
      halfx8 bf = *(const halfx8*)(zrow + brow * 2);
      halfx8 a0 = *(const halfx8*)(arow0 + acol * 2);
      halfx8 a1 = *(const halfx8*)(arow1 + acol * 2);
      if (ks < 4) {
        hi0 = MFMA(a0, bf, hi0);
        hi1 = MFMA(a1, bf, hi1);
      } else {
        lo0 = MFMA(a0, bf, lo0);
        lo1 = MFMA(a1, bf, lo1);
      }
    }
    // gate + fp16 split (into registers; gT written after barrier)
#pragma unroll
    for (int r = 0; r < 16; ++r) {
      float ha = hi0[r] + lo0[r] * (1.f / 2048.f);
      float hb = hi1[r] + lo1[r] * (1.f / 2048.f);
      ha = fmaxf(ha, -30.f);
      hb = fmaxf(hb, -30.f);
      float ea = __expf(-ha), eb = __expf(-hb);
      float ga = (1.f - ea) / (1.f + ea * ea);   // tanh(h)*sigmoid(h)
      float gb = (1.f - eb) / (1.f + eb * eb);
      half_t ga0 = (half_t)ga;
      half_t ga1 = (half_t)((ga - (float)ga0) * 2048.f);
      half_t gb0 = (half_t)gb;
      half_t gb1 = (half_t)((gb - (float)gb0) * 2048.f);
      t0h[r >> 2][r & 3] = ga0;
      t0l[r >> 2][r & 3] = ga1;
      t1h[r >> 2][r & 3] = gb0;
      t1l[r >> 2][r & 3] = gb1;
    }
  }
  __syncthreads();   // Wa/zT reads complete

  // ---- write gT (overlays Wa): rows(K): 0..127 g-hi, 128..255 g-lo*2048 ----
  {
    int mh = wave & 1, nh = wave >> 1;
    int colt = nh * 32 + l31;
    char* grow = sm + GT_OFF + colt * 528;
#pragma unroll
    for (int rg = 0; rg < 4; ++rg) {
      int m0 = mh * 64 + 8 * rg + 4 * lhi;
      int m1 = m0 + 32;
      *(halfx4*)(grow + m0 * 2)          = t0h[rg];
      *(halfx4*)(grow + m1 * 2)          = t1h[rg];
      *(halfx4*)(grow + (128 + m0) * 2)  = t0l[rg];
      *(halfx4*)(grow + (128 + m1) * 2)  = t1l[rg];
    }
  }
  __syncthreads();

  // ---- GEMM2: skip[32,64] = Wr @ g, K=384 effective, split over 2 K-halves ----
  f32x16 shi{}, slo{};
  {
    int nh = wave & 1, kh = wave >> 1;
    int colt = nh * 32 + l31;
    const char* grow = sm + GT_OFF + colt * 528 + lhi * 16;
    const char* arow = sm + WR_OFF + l31 * 528 + lhi * 16;
    if (kh == 0) {
#pragma unroll
      for (int ks = 0; ks < 12; ++ks) {
        int acol = (ks & 7) * 16;
        int brow = (ks < 8) ? ks * 16 : (ks - 8) * 16 + 128;
        halfx8 a  = *(const halfx8*)(arow + acol * 2);
        halfx8 bf = *(const halfx8*)(grow + brow * 2);
        if (ks < 8) shi = MFMA(a, bf, shi);
        else        slo = MFMA(a, bf, slo);
      }
    } else {
#pragma unroll
      for (int ks = 0; ks < 12; ++ks) {
        int gks = 12 + ks;
        int acol = (gks < 16) ? (gks & 7) * 16 : (gks - 16) * 16 + 128;
        int brow = (gks < 16) ? (gks - 8) * 16 + 128 : (gks - 16) * 16;
        halfx8 a  = *(const halfx8*)(arow + acol * 2);
        halfx8 bf = *(const halfx8*)(grow + brow * 2);
        slo = MFMA(a, bf, slo);
      }
    }
  }
  // ---- skip partials to LDS (overlays zT) ----
  {
    int nh = wave & 1, kh = wave >> 1;
    float* skb = (float*)(sm + SKB_OFF) + kh * 32 * 68;
    int colt = nh * 32 + l31;
#pragma unroll
    for (int r = 0; r < 16; ++r) {
      int row = (r & 3) + 8 * (r >> 2) + 4 * lhi;
      skb[row * 68 + colt] = shi[r] + slo[r] * (1.f / 2048.f);
    }
  }
  __syncthreads();

  // ---- writeout: resOut = resIn + skip ----
  {
    int c = tid >> 3, tt = (tid & 7) * 8;
    const float* s0 = (const float*)(sm + SKB_OFF) + c * 68 + tt;
    const float* s1 = s0 + 32 * 68;
    size_t base = ((size_t)b * 32 + c) * T_LEN + t0 + tt;
#pragma unroll
    for (int v = 0; v < 8; v += 4) {
      float4 sa = *(const float4*)(s0 + v);
      float4 sb = *(const float4*)(s1 + v);
      float4 ri = *(const float4*)(resIn + base + v);
      float4 o;
      o.x = ri.x + sa.x + sb.x;
      o.y = ri.y + sa.y + sb.y;
      o.z = ri.z + sa.z + sb.z;
      o.w = ri.w + sa.w + sb.w;
      *(float4*)(resOut + base + v) = o;
    }
  }
}

// ---------------- end: relu(resF - res0) -> relu(We1 @ .) -> We2 @ . ----------------
__global__ __launch_bounds__(256) void end_k(const float* __restrict__ resF,
                                             const float* __restrict__ res0,
                                             const float* __restrict__ We1T,
                                             const float* __restrict__ We2T,
                                             float* __restrict__ out) {
  __shared__ float h1[32][68];
  __shared__ float h2[256][68];
  int b = blockIdx.x / NTILE;
  int t0 = (blockIdx.x % NTILE) * TT;
  int tid = threadIdx.x;
  int lr = tid >> 3, lt = (tid & 7) * 8;
  {
    size_t base = ((size_t)b * 32 + lr) * T_LEN + t0 + lt;
    float4 f0 = *(const float4*)(resF + base);
    float4 f1 = *(const float4*)(resF + base + 4);
    float4 z0 = *(const float4*)(res0 + base);
    float4 z1 = *(const float4*)(res0 + base + 4);
    h1[lr][lt]     = fmaxf(f0.x - z0.x, 0.f);
    h1[lr][lt + 1] = fmaxf(f0.y - z0.y, 0.f);
    h1[lr][lt + 2] = fmaxf(f0.z - z0.z, 0.f);
    h1[lr][lt + 3] = fmaxf(f0.w - z0.w, 0.f);
    h1[lr][lt + 4] = fmaxf(f1.x - z1.x, 0.f);
    h1[lr][lt + 5] = fmaxf(f1.y - z1.y, 0.f);
    h1[lr][lt + 6] = fmaxf(f1.z - z1.z, 0.f);
    h1[lr][lt + 7] = fmaxf(f1.w - z1.w, 0.f);
  }
  __syncthreads();
  int og = tid & 63, tg = (tid >> 6) * 16;
  float acc[4][16];
#pragma unroll
  for (int jj = 0; jj < 4; ++jj)
#pragma unroll
    for (int t = 0; t < 16; ++t) acc[jj][t] = 0.f;
  for (int c = 0; c < 32; ++c) {
    float w[4];
#pragma unroll
    for (int jj = 0; jj < 4; ++jj) w[jj] = We1T[c * 256 + jj * 64 + og];
    const float* hr = &h1[c][tg];
#pragma unroll
    for (int t = 0; t < 16; ++t) {
      float xv = hr[t];
#pragma unroll
      for (int jj = 0; jj < 4; ++jj) acc[jj][t] += w[jj] * xv;
    }
  }
#pragma unroll
  for (int jj = 0; jj < 4; ++jj)
#pragma unroll
    for (int t = 0; t < 16; t += 4)
      *(float4*)&h2[jj * 64 + og][tg + t] =
          make_float4(fmaxf(acc[jj][t], 0.f), fmaxf(acc[jj][t + 1], 0.f),
                      fmaxf(acc[jj][t + 2], 0.f), fmaxf(acc[jj][t + 3], 0.f));
  __syncthreads();
  float a2[4][16];
#pragma unroll
  for (int jj = 0; jj < 4; ++jj)
#pragma unroll
    for (int t = 0; t < 16; ++t) a2[jj][t] = 0.f;
  for (int c = 0; c < 256; ++c) {
    float w[4];
#pragma unroll
    for (int jj = 0; jj < 4; ++jj) w[jj] = We2T[c * 256 + jj * 64 + og];
    const float* hr = &h2[c][tg];
#pragma unroll
    for (int t = 0; t < 16; ++t) {
      float xv = hr[t];
#pragma unroll
      for (int jj = 0; jj < 4; ++jj) a2[jj][t] += w[jj] * xv;
    }
  }
#pragma unroll
  for (int jj = 0; jj < 4; ++jj) {
    float* op = out + ((size_t)b * 256 + jj * 64 + og) * T_LEN + t0 + tg;
#pragma unroll
    for (int t = 0; t < 16; t += 4)
      *(float4*)(op + t) =
          make_float4(a2[jj][t], a2[jj][t + 1], a2[jj][t + 2], a2[jj][t + 3]);
  }
}

extern "C" void kernel_launch(void* const* d_in, const int* in_sizes, int n_in,
                              void* d_out, int out_size, void* d_ws, size_t ws_size,
                              hipStream_t stream) {
  const float* x   = (const float*)d_in[0];
  const float* Wst = (const float*)d_in[1];
  const float* Wd  = (const float*)d_in[2];
  const float* Wr  = (const float*)d_in[3];
  const float* We1 = (const float*)d_in[4];
  const float* We2 = (const float*)d_in[5];
  float* out = (float*)d_out;
  float* ws = (float*)d_ws;

  float* resA = ws;                    // start output (preserved; skips = resF - resA)
  float* resB = resA + N_RES;
  float* resC = resB + N_RES;
  half_t* WaG = (half_t*)(resC + N_RES);   // 40 * 128*128 fp16
  half_t* WrG = WaG + 40 * 16384;          // 40 * 32*256 fp16
  float* WsT  = (float*)(WrG + 40 * 8192);
  float* We1T = WsT + 8192;
  float* We2T = We1T + 8192;

  repack_k<<<2560, 256, 0, stream>>>(Wd, Wr, Wst, We1, We2, WaG, WrG, WsT, We1T, We2T);
  start_k<<<NBLK, 256, 0, stream>>>(x, WsT, resA);

  const float* rin = resA;
  for (int l = 0; l < 40; ++l) {
    float* rout = (l & 1) ? resC : resB;
    layer_k<<<NBLK, 256, 0, stream>>>(rin, rout, WaG + l * 16384, WrG + l * 8192,
                                      1 << (l % 10));
    rin = rout;
  }
  end_k<<<NBLK, 256, 0, stream>>>(rin, resA, We1T, We2T, out);
}

// Round 3
// 1464.362 us; speedup vs baseline: 2.1951x; 1.1281x over previous
//
#include <hip/hip_runtime.h>
#include <math.h>

#define T_LEN 16000
#define NTILE 250          // time tiles per batch row (16000/64)
#define TT 64              // time tile
#define NBLK 2000          // 8 * 250

static const int N_RES = 8 * 32 * T_LEN;   // 4,096,000 floats per residual buffer

typedef _Float16 half_t;
typedef __attribute__((ext_vector_type(8))) _Float16 halfx8;
typedef __attribute__((ext_vector_type(4))) _Float16 halfx4;
typedef __attribute__((ext_vector_type(16))) float f32x16;

#define MFMA(a, b, c) __builtin_amdgcn_mfma_f32_32x32x16_f16((a), (b), (c), 0, 0, 0)

// ---------------- weight repack ----------------
// WaG[l][o=0..127][c=0..127] fp16: c<64 hi of Wd[l][o][c&31][c>>5], c>=64 lo*2048
// WrG[l][o2=0..31][c=0..255] fp16: c<128 hi of Wr[l][c][o2], c>=128 lo*2048
// We1S[o=0..255][k=0..63]   fp16: k<32 hi of We1[o][k], k>=32 lo*2048
// We2S[o=0..255][k=0..511]  fp16: k<256 hi of We2[o][k], k>=256 lo*2048
__global__ __launch_bounds__(256) void repack_k(
    const float* __restrict__ Wd, const float* __restrict__ Wr,
    const float* __restrict__ Ws, const float* __restrict__ We1,
    const float* __restrict__ We2,
    half_t* __restrict__ WaG, half_t* __restrict__ WrG, float* __restrict__ WsT,
    half_t* __restrict__ We1S, half_t* __restrict__ We2S) {
  int i = blockIdx.x * 256 + threadIdx.x;
  if (i < 40 * 128 * 128) {
    int l = i >> 14, r = i & 16383, o = r >> 7, c = r & 127;
    int cb = c & 63, chan = cb & 31, tap = cb >> 5;
    float w = Wd[(((l * 128 + o) * 32 + chan) << 1) + tap];
    half_t w0 = (half_t)w;
    WaG[i] = (c < 64) ? w0 : (half_t)((w - (float)w0) * 2048.f);
  }
  if (i < 40 * 32 * 256) {
    int l = i >> 13, r = i & 8191, o = r >> 8, c = r & 255;
    int cb = c & 127;
    float w = Wr[(l * 32 + o) * 128 + cb];
    half_t w0 = (half_t)w;
    WrG[i] = (c < 128) ? w0 : (half_t)((w - (float)w0) * 2048.f);
  }
  // WsT[c][o] <- Ws[o][c]  (256x32)
  if (i < 8192) {
    int c = i >> 5, o = i & 31;
    WsT[i] = Ws[o * 256 + c];
  }
  if (i < 16384) {
    int o = i >> 6, k = i & 63;
    float w = We1[o * 32 + (k & 31)];
    half_t w0 = (half_t)w;
    We1S[i] = (k < 32) ? w0 : (half_t)((w - (float)w0) * 2048.f);
  }
  if (i < 131072) {
    int o = i >> 9, k = i & 511;
    float w = We2[o * 256 + (k & 255)];
    half_t w0 = (half_t)w;
    We2S[i] = (k < 256) ? w0 : (half_t)((w - (float)w0) * 2048.f);
  }
}

// ---------------- start 1x1 conv (f32): residual = W_start @ x ----------------
__global__ __launch_bounds__(256) void start_k(const float* __restrict__ x,
                                               const float* __restrict__ WsT,
                                               float* __restrict__ res) {
  __shared__ float xs[32][68];
  int b = blockIdx.x / NTILE;
  int t0 = (blockIdx.x % NTILE) * TT;
  int tid = threadIdx.x;
  int o = tid & 31, tg = (tid >> 5) * 8;
  int lr = tid >> 3, lt = (tid & 7) * 8;
  float acc[8];
#pragma unroll
  for (int j = 0; j < 8; ++j) acc[j] = 0.f;
  for (int cc = 0; cc < 8; ++cc) {
    __syncthreads();
    const float* xp = x + ((size_t)b * 256 + cc * 32 + lr) * T_LEN + t0 + lt;
    *(float4*)&xs[lr][lt]     = *(const float4*)xp;
    *(float4*)&xs[lr][lt + 4] = *(const float4*)(xp + 4);
    __syncthreads();
#pragma unroll 4
    for (int c = 0; c < 32; ++c) {
      float w = WsT[(cc * 32 + c) * 32 + o];
      const float* xr = &xs[c][tg];
#pragma unroll
      for (int j = 0; j < 8; ++j) acc[j] += w * xr[j];
    }
  }
  float* rp = res + ((size_t)b * 32 + o) * T_LEN + t0 + tg;
  *(float4*)rp       = make_float4(acc[0], acc[1], acc[2], acc[3]);
  *(float4*)(rp + 4) = make_float4(acc[4], acc[5], acc[6], acc[7]);
}

// ---------------- fused WaveNet layer: MFMA fp16 split-2 ----------------
// LDS map (bytes), aliased by phase:
//   [0     .. 34816)  Wa   128 rows x 272B      | phase B: gT 64 rows x 528B
//   [34816 .. 52224)  zT    64 rows x 272B      | phase C: skb 2 x 32 x 68 f32
//   [52224 .. 69120)  Wr2   32 rows x 528B
//   [69120 .. 77824)  cur32 32 x 68 f32 (residual kept f32 for writeout)
__global__ __launch_bounds__(256) void layer_k(const float* __restrict__ resIn,
                                               float* __restrict__ resOut,
                                               const half_t* __restrict__ WaL,
                                               const half_t* __restrict__ WrL, int d) {
  __shared__ __align__(16) char sm[77824];
  const int WA_OFF = 0, ZT_OFF = 34816, WR_OFF = 52224, GT_OFF = 0, SKB_OFF = 34816,
            CUR_OFF = 69120;
  int tid = threadIdx.x;
  int b = blockIdx.x / NTILE;
  int t0 = (blockIdx.x % NTILE) * TT;

  // ---- stage Wa (32KB) ----
  {
    int row = tid >> 1, hf = tid & 1;
    const float4* src = (const float4*)(WaL + row * 128 + hf * 64);
    char* dst = sm + WA_OFF + row * 272 + hf * 128;
#pragma unroll
    for (int j = 0; j < 8; ++j) *(float4*)(dst + j * 16) = src[j];
  }
  // ---- stage Wr2 (16KB) ----
  {
    int row = tid >> 3, chunk = tid & 7;
    const float4* src = (const float4*)(WrL + row * 256 + chunk * 32);
    char* dst = sm + WR_OFF + row * 528 + chunk * 64;
#pragma unroll
    for (int j = 0; j < 4; ++j) *(float4*)(dst + j * 16) = src[j];
  }
  // ---- stage zT + cur32 ----
  {
    int c = tid >> 3, tt = (tid & 7) * 8;
    const float* rip = resIn + ((size_t)b * 32 + c) * T_LEN;
    float cv[8], pv[8];
    *(float4*)cv       = *(const float4*)(rip + t0 + tt);
    *(float4*)(cv + 4) = *(const float4*)(rip + t0 + tt + 4);
    int tp = t0 + tt - d;
    if (tp >= 0 && (d & 3) == 0) {
      *(float4*)pv       = *(const float4*)(rip + tp);
      *(float4*)(pv + 4) = *(const float4*)(rip + tp + 4);
    } else {
#pragma unroll
      for (int j = 0; j < 8; ++j) {
        int q = tp + j;
        pv[j] = (q >= 0) ? rip[q] : 0.f;
      }
    }
    float* cw = (float*)(sm + CUR_OFF) + c * 68 + tt;
    *(float4*)cw       = *(const float4*)cv;
    *(float4*)(cw + 4) = *(const float4*)(cv + 4);
#pragma unroll
    for (int j = 0; j < 8; ++j) {
      half_t* zrow = (half_t*)(sm + ZT_OFF + (tt + j) * 272);
      half_t p0 = (half_t)pv[j];
      half_t p1 = (half_t)((pv[j] - (float)p0) * 2048.f);
      half_t c0 = (half_t)cv[j];
      half_t c1 = (half_t)((cv[j] - (float)c0) * 2048.f);
      zrow[c]      = p0;
      zrow[c + 32] = c0;
      zrow[c + 64] = p1;
      zrow[c + 96] = c1;
    }
  }
  __syncthreads();

  int wave = tid >> 6, lane = tid & 63;
  int l31 = lane & 31, lhi = lane >> 5;

  // ---- GEMM1: h[128,64] = W @ z, split-2 (12 K-steps of 16) ----
  halfx4 t0h[4], t0l[4], t1h[4], t1l[4];
  {
    int mh = wave & 1, nh = wave >> 1;
    int colt = nh * 32 + l31;
    const char* zrow  = sm + ZT_OFF + colt * 272 + lhi * 16;
    const char* arow0 = sm + WA_OFF + (mh * 64 + l31) * 272 + lhi * 16;
    const char* arow1 = arow0 + 32 * 272;
    f32x16 hi0{}, hi1{}, lo0{}, lo1{};
#pragma unroll
    for (int ks = 0; ks < 12; ++ks) {
      int acol = (ks < 8) ? (ks & 3) * 16 : (ks & 3) * 16 + 64;
      int brow = (ks < 4) ? ks * 16 : ((ks < 8) ? (ks & 3) * 16 + 64 : (ks & 3) * 16);
      halfx8 bf = *(const halfx8*)(zrow + brow * 2);
      halfx8 a0 = *(const halfx8*)(arow0 + acol * 2);
      halfx8 a1 = *(const halfx8*)(arow1 + acol * 2);
      if (ks < 4) {
        hi0 = MFMA(a0, bf, hi0);
        hi1 = MFMA(a1, bf, hi1);
      } else {
        lo0 = MFMA(a0, bf, lo0);
        lo1 = MFMA(a1, bf, lo1);
      }
    }
#pragma unroll
    for (int r = 0; r < 16; ++r) {
      float ha = hi0[r] + lo0[r] * (1.f / 2048.f);
      float hb = hi1[r] + lo1[r] * (1.f / 2048.f);
      ha = fmaxf(ha, -30.f);
      hb = fmaxf(hb, -30.f);
      float ea = __expf(-ha), eb = __expf(-hb);
      float ga = (1.f - ea) / (1.f + ea * ea);
      float gb = (1.f - eb) / (1.f + eb * eb);
      half_t ga0 = (half_t)ga;
      half_t ga1 = (half_t)((ga - (float)ga0) * 2048.f);
      half_t gb0 = (half_t)gb;
      half_t gb1 = (half_t)((gb - (float)gb0) * 2048.f);
      t0h[r >> 2][r & 3] = ga0;
      t0l[r >> 2][r & 3] = ga1;
      t1h[r >> 2][r & 3] = gb0;
      t1l[r >> 2][r & 3] = gb1;
    }
  }
  __syncthreads();

  // ---- write gT (overlays Wa) ----
  {
    int mh = wave & 1, nh = wave >> 1;
    int colt = nh * 32 + l31;
    char* grow = sm + GT_OFF + colt * 528;
#pragma unroll
    for (int rg = 0; rg < 4; ++rg) {
      int m0 = mh * 64 + 8 * rg + 4 * lhi;
      int m1 = m0 + 32;
      *(halfx4*)(grow + m0 * 2)          = t0h[rg];
      *(halfx4*)(grow + m1 * 2)          = t1h[rg];
      *(halfx4*)(grow + (128 + m0) * 2)  = t0l[rg];
      *(halfx4*)(grow + (128 + m1) * 2)  = t1l[rg];
    }
  }
  __syncthreads();

  // ---- GEMM2: skip[32,64] = Wr @ g, K-split over wave pairs ----
  f32x16 shi{}, slo{};
  {
    int nh = wave & 1, kh = wave >> 1;
    int colt = nh * 32 + l31;
    const char* grow = sm + GT_OFF + colt * 528 + lhi * 16;
    const char* arow = sm + WR_OFF + l31 * 528 + lhi * 16;
    if (kh == 0) {
#pragma unroll
      for (int ks = 0; ks < 12; ++ks) {
        int acol = (ks & 7) * 16;
        int brow = (ks < 8) ? ks * 16 : (ks - 8) * 16 + 128;
        halfx8 a  = *(const halfx8*)(arow + acol * 2);
        halfx8 bf = *(const halfx8*)(grow + brow * 2);
        if (ks < 8) shi = MFMA(a, bf, shi);
        else        slo = MFMA(a, bf, slo);
      }
    } else {
#pragma unroll
      for (int ks = 0; ks < 12; ++ks) {
        int gks = 12 + ks;
        int acol = (gks < 16) ? (gks & 7) * 16 : (gks - 16) * 16 + 128;
        int brow = (gks < 16) ? (gks - 8) * 16 + 128 : (gks - 16) * 16;
        halfx8 a  = *(const halfx8*)(arow + acol * 2);
        halfx8 bf = *(const halfx8*)(grow + brow * 2);
        slo = MFMA(a, bf, slo);
      }
    }
  }
  // ---- skip partials to LDS (overlays zT) ----
  {
    int nh = wave & 1, kh = wave >> 1;
    float* skb = (float*)(sm + SKB_OFF) + kh * 32 * 68;
    int colt = nh * 32 + l31;
#pragma unroll
    for (int r = 0; r < 16; ++r) {
      int row = (r & 3) + 8 * (r >> 2) + 4 * lhi;
      skb[row * 68 + colt] = shi[r] + slo[r] * (1.f / 2048.f);
    }
  }
  __syncthreads();

  // ---- writeout: resOut = cur + skip (all from LDS) ----
  {
    int c = tid >> 3, tt = (tid & 7) * 8;
    const float* s0 = (const float*)(sm + SKB_OFF) + c * 68 + tt;
    const float* s1 = s0 + 32 * 68;
    const float* cu = (const float*)(sm + CUR_OFF) + c * 68 + tt;
    size_t base = ((size_t)b * 32 + c) * T_LEN + t0 + tt;
#pragma unroll
    for (int v = 0; v < 8; v += 4) {
      float4 sa = *(const float4*)(s0 + v);
      float4 sb = *(const float4*)(s1 + v);
      float4 cv = *(const float4*)(cu + v);
      float4 o;
      o.x = cv.x + sa.x + sb.x;
      o.y = cv.y + sa.y + sb.y;
      o.z = cv.z + sa.z + sb.z;
      o.w = cv.w + sa.w + sb.w;
      *(float4*)(resOut + base + v) = o;
    }
  }
}

// ---------------- end: relu(resF-res0) -> relu(We1@.) -> We2@. , MFMA split-2 ----------------
// 512 threads / 8 waves; wave = m-tile. LDS:
//   [0, 66560)      h2T [64 t][520 halves] (k<256 hi, 256.. lo)  | alias: h1f32 [32][68] f32
//   [66560, 75776)  h1T [64 t][72 halves]  (k<32 hi, 32.. lo)
__global__ __launch_bounds__(512) void end_k(const float* __restrict__ resF,
                                             const float* __restrict__ res0,
                                             const half_t* __restrict__ We1S,
                                             const half_t* __restrict__ We2S,
                                             float* __restrict__ out) {
  __shared__ __align__(16) char sm[75776];
  const int H2T_OFF = 0, H1F_OFF = 0, H1T_OFF = 66560;
  int tid = threadIdx.x;
  int b = blockIdx.x / NTILE;
  int t0 = (blockIdx.x % NTILE) * TT;

  // stage h1f32 = relu(resF - res0)
  {
    int c = tid >> 4, tt4 = (tid & 15) * 4;
    size_t base = ((size_t)b * 32 + c) * T_LEN + t0 + tt4;
    float4 f = *(const float4*)(resF + base);
    float4 z = *(const float4*)(res0 + base);
    float* h1 = (float*)(sm + H1F_OFF) + c * 68 + tt4;
    h1[0] = fmaxf(f.x - z.x, 0.f);
    h1[1] = fmaxf(f.y - z.y, 0.f);
    h1[2] = fmaxf(f.z - z.z, 0.f);
    h1[3] = fmaxf(f.w - z.w, 0.f);
  }
  __syncthreads();
  // build h1T fp16 splits
  {
    int t = tid & 63, cg = tid >> 6;
    const float* h1 = (const float*)(sm + H1F_OFF);
    halfx4 hi, lo;
#pragma unroll
    for (int j = 0; j < 4; ++j) {
      float v = h1[(cg * 4 + j) * 68 + t];
      half_t h = (half_t)v;
      hi[j] = h;
      lo[j] = (half_t)((v - (float)h) * 2048.f);
    }
    half_t* h1t = (half_t*)(sm + H1T_OFF) + t * 72;
    *(halfx4*)(h1t + cg * 4)      = hi;
    *(halfx4*)(h1t + 32 + cg * 4) = lo;
  }
  __syncthreads();

  int wave = tid >> 6, lane = tid & 63;
  int l31 = lane & 31, lhi = lane >> 5;

  // ---- e1: h2[256,64] = We1 @ h1 (K=32 split) ----
  f32x16 aHi0{}, aHi1{}, aLo0{}, aLo1{};
  {
    const char* h1t = sm + H1T_OFF;
    const half_t* wp = We1S + (wave * 32 + l31) * 64;
#pragma unroll
    for (int ks = 0; ks < 2; ++ks) {
      halfx8 hiA = *(const halfx8*)(wp + ks * 16 + lhi * 8);
      halfx8 loA = *(const halfx8*)(wp + 32 + ks * 16 + lhi * 8);
      const char* br0 = h1t + l31 * 144;
      const char* br1 = h1t + (32 + l31) * 144;
      halfx8 hiB0 = *(const halfx8*)(br0 + (ks * 16 + lhi * 8) * 2);
      halfx8 loB0 = *(const halfx8*)(br0 + (32 + ks * 16 + lhi * 8) * 2);
      halfx8 hiB1 = *(const halfx8*)(br1 + (ks * 16 + lhi * 8) * 2);
      halfx8 loB1 = *(const halfx8*)(br1 + (32 + ks * 16 + lhi * 8) * 2);
      aHi0 = MFMA(hiA, hiB0, aHi0);
      aLo0 = MFMA(hiA, loB0, aLo0);
      aLo0 = MFMA(loA, hiB0, aLo0);
      aHi1 = MFMA(hiA, hiB1, aHi1);
      aLo1 = MFMA(hiA, loB1, aLo1);
      aLo1 = MFMA(loA, hiB1, aLo1);
    }
  }
  // write h2T = relu(h2) splits (region 0; h1f32 dead, disjoint from h1T)
  {
#pragma unroll
    for (int n = 0; n < 2; ++n) {
      const f32x16& aH = n ? aHi1 : aHi0;
      const f32x16& aL = n ? aLo1 : aLo0;
      int t = n * 32 + l31;
      half_t* row = (half_t*)(sm + H2T_OFF) + t * 520;
#pragma unroll
      for (int g = 0; g < 4; ++g) {
        halfx4 hi, lo;
#pragma unroll
        for (int j = 0; j < 4; ++j) {
          int r = g * 4 + j;
          float v = aH[r] + aL[r] * (1.f / 2048.f);
          v = fmaxf(v, 0.f);
          half_t h = (half_t)v;
          hi[j] = h;
          lo[j] = (half_t)((v - (float)h) * 2048.f);
        }
        int col = wave * 32 + g * 8 + lhi * 4;
        *(halfx4*)(row + col)       = hi;
        *(halfx4*)(row + 256 + col) = lo;
      }
    }
  }
  __syncthreads();

  // ---- e2: out[256,64] = We2 @ h2 (K=256 split), A from global (L2-hot) ----
  f32x16 bHi0{}, bHi1{}, bLo0{}, bLo1{};
  {
    const half_t* wp = We2S + (size_t)(wave * 32 + l31) * 512;
    const char* h2t = sm + H2T_OFF;
#pragma unroll 2
    for (int ks = 0; ks < 16; ++ks) {
      halfx8 hiA = *(const halfx8*)(wp + ks * 16 + lhi * 8);
      halfx8 loA = *(const halfx8*)(wp + 256 + ks * 16 + lhi * 8);
      const char* br0 = h2t + l31 * 1040;
      const char* br1 = h2t + (32 + l31) * 1040;
      halfx8 hiB0 = *(const halfx8*)(br0 + (ks * 16 + lhi * 8) * 2);
      halfx8 loB0 = *(const halfx8*)(br0 + (256 + ks * 16 + lhi * 8) * 2);
      halfx8 hiB1 = *(const halfx8*)(br1 + (ks * 16 + lhi * 8) * 2);
      halfx8 loB1 = *(const halfx8*)(br1 + (256 + ks * 16 + lhi * 8) * 2);
      bHi0 = MFMA(hiA, hiB0, bHi0);
      bLo0 = MFMA(hiA, loB0, bLo0);
      bLo0 = MFMA(loA, hiB0, bLo0);
      bHi1 = MFMA(hiA, hiB1, bHi1);
      bLo1 = MFMA(hiA, loB1, bLo1);
      bLo1 = MFMA(loA, hiB1, bLo1);
    }
  }
  // write out
  {
#pragma unroll
    for (int n = 0; n < 2; ++n) {
      const f32x16& bH = n ? bHi1 : bHi0;
      const f32x16& bL = n ? bLo1 : bLo0;
      int t = t0 + n * 32 + l31;
#pragma unroll
      for (int r = 0; r < 16; ++r) {
        int o = wave * 32 + (r & 3) + 8 * (r >> 2) + 4 * lhi;
        out[((size_t)b * 256 + o) * T_LEN + t] = bH[r] + bL[r] * (1.f / 2048.f);
      }
    }
  }
}

extern "C" void kernel_launch(void* const* d_in, const int* in_sizes, int n_in,
                              void* d_out, int out_size, void* d_ws, size_t ws_size,
                              hipStream_t stream) {
  const float* x   = (const float*)d_in[0];
  const float* Wst = (const float*)d_in[1];
  const float* Wd  = (const float*)d_in[2];
  const float* Wr  = (const float*)d_in[3];
  const float* We1 = (const float*)d_in[4];
  const float* We2 = (const float*)d_in[5];
  float* out = (float*)d_out;
  float* ws = (float*)d_ws;

  float* resA = ws;                        // start output (skips = resF - resA)
  float* resB = resA + N_RES;
  float* resC = resB + N_RES;
  half_t* WaG  = (half_t*)(resC + N_RES);  // 40*16384
  half_t* WrG  = WaG + 40 * 16384;         // 40*8192
  float*  WsT  = (float*)(WrG + 40 * 8192);
  half_t* We1S = (half_t*)(WsT + 8192);    // 16384
  half_t* We2S = We1S + 16384;             // 131072

  repack_k<<<2560, 256, 0, stream>>>(Wd, Wr, Wst, We1, We2, WaG, WrG, WsT, We1S, We2S);
  start_k<<<NBLK, 256, 0, stream>>>(x, WsT, resA);

  const float* rin = resA;
  for (int l = 0; l < 40; ++l) {
    float* rout = (l & 1) ? resC : resB;
    layer_k<<<NBLK, 256, 0, stream>>>(rin, rout, WaG + l * 16384, WrG + l * 8192,
                                      1 << (l % 10));
    rin = rout;
  }
  end_k<<<NBLK, 512, 0, stream>>>(rin, resA, We1S, We2S, out);
}

// Round 4
// 1181.220 us; speedup vs baseline: 2.7213x; 1.2397x over previous
//
#include <hip/hip_runtime.h>
#include <math.h>

#define T_LEN 16000
#define NTILE 250          // time tiles per batch row (16000/64)
#define TT 64              // time tile
#define NBLK 2000          // 8 * 250
#define LGRID 500          // layer grid: 4 strided tiles per block

static const int N_RES = 8 * 32 * T_LEN;   // 4,096,000 floats per residual buffer

typedef _Float16 half_t;
typedef __attribute__((ext_vector_type(8))) _Float16 halfx8;
typedef __attribute__((ext_vector_type(4))) _Float16 halfx4;
typedef __attribute__((ext_vector_type(16))) float f32x16;
typedef unsigned int uint32;
typedef unsigned short ushort16;

#define MFMA(a, b, c) __builtin_amdgcn_mfma_f32_32x32x16_f16((a), (b), (c), 0, 0, 0)

static __device__ inline uint32 packpair(float a, float b) {
  half_t ha = (half_t)a, hb = (half_t)b;
  return (uint32)__builtin_bit_cast(ushort16, ha) |
         ((uint32)__builtin_bit_cast(ushort16, hb) << 16);
}

// ---------------- weight repack ----------------
// WaG[l][o=0..127][k=0..127]: k<64: k=2c+s -> hi(Wd[l][o][c][s]); k>=64: lo*2048 of same (k-64 pairing)
// WrG[l][o2=0..31][k=0..255]: kk=k&127 -> m via gT-perm; k<128 hi, k>=128 lo*2048
//   perm: mh=kk>>6; j2=kk&63; til=j2>>5; j=j2&31; lh=j>>4; rr=j&15; m=mh*64+til*32+(rr&3)+(rr>>2)*8+lh*4
// We1S[o][k=0..63]: k<32 hi We1[o][k], k>=32 lo*2048
// We2S[o][k=0..511]: k<256 hi We2[o][k], k>=256 lo*2048
__global__ __launch_bounds__(256) void repack_k(
    const float* __restrict__ Wd, const float* __restrict__ Wr,
    const float* __restrict__ Ws, const float* __restrict__ We1,
    const float* __restrict__ We2,
    half_t* __restrict__ WaG, half_t* __restrict__ WrG, float* __restrict__ WsT,
    half_t* __restrict__ We1S, half_t* __restrict__ We2S) {
  int i = blockIdx.x * 256 + threadIdx.x;
  if (i < 40 * 128 * 128) {
    int l = i >> 14, r = i & 16383, o = r >> 7, k = r & 127;
    int kk = k & 63, c = kk >> 1, s = kk & 1;
    float w = Wd[(((l * 128 + o) * 32 + c) << 1) + s];
    half_t w0 = (half_t)w;
    WaG[i] = (k < 64) ? w0 : (half_t)((w - (float)w0) * 2048.f);
  }
  if (i < 40 * 32 * 256) {
    int l = i >> 13, r = i & 8191, o2 = r >> 8, k = r & 255;
    int kk = k & 127;
    int mh = kk >> 6, j2 = kk & 63, til = j2 >> 5, j = j2 & 31, lh = j >> 4, rr = j & 15;
    int m = mh * 64 + til * 32 + (rr & 3) + ((rr >> 2) << 3) + lh * 4;
    float w = Wr[(l * 32 + o2) * 128 + m];
    half_t w0 = (half_t)w;
    WrG[i] = (k < 128) ? w0 : (half_t)((w - (float)w0) * 2048.f);
  }
  if (i < 8192) {
    int c = i >> 5, o = i & 31;
    WsT[i] = Ws[o * 256 + c];
  }
  if (i < 16384) {
    int o = i >> 6, k = i & 63;
    float w = We1[o * 32 + (k & 31)];
    half_t w0 = (half_t)w;
    We1S[i] = (k < 32) ? w0 : (half_t)((w - (float)w0) * 2048.f);
  }
  if (i < 131072) {
    int o = i >> 9, k = i & 511;
    float w = We2[o * 256 + (k & 255)];
    half_t w0 = (half_t)w;
    We2S[i] = (k < 256) ? w0 : (half_t)((w - (float)w0) * 2048.f);
  }
}

// ---------------- start 1x1 conv (f32): residual = W_start @ x ----------------
__global__ __launch_bounds__(256) void start_k(const float* __restrict__ x,
                                               const float* __restrict__ WsT,
                                               float* __restrict__ res) {
  __shared__ float xs[32][68];
  int b = blockIdx.x / NTILE;
  int t0 = (blockIdx.x % NTILE) * TT;
  int tid = threadIdx.x;
  int o = tid & 31, tg = (tid >> 5) * 8;
  int lr = tid >> 3, lt = (tid & 7) * 8;
  float acc[8];
#pragma unroll
  for (int j = 0; j < 8; ++j) acc[j] = 0.f;
  for (int cc = 0; cc < 8; ++cc) {
    __syncthreads();
    const float* xp = x + ((size_t)b * 256 + cc * 32 + lr) * T_LEN + t0 + lt;
    *(float4*)&xs[lr][lt]     = *(const float4*)xp;
    *(float4*)&xs[lr][lt + 4] = *(const float4*)(xp + 4);
    __syncthreads();
#pragma unroll 4
    for (int c = 0; c < 32; ++c) {
      float w = WsT[(cc * 32 + c) * 32 + o];
      const float* xr = &xs[c][tg];
#pragma unroll
      for (int j = 0; j < 8; ++j) acc[j] += w * xr[j];
    }
  }
  float* rp = res + ((size_t)b * 32 + o) * T_LEN + t0 + tg;
  *(float4*)rp       = make_float4(acc[0], acc[1], acc[2], acc[3]);
  *(float4*)(rp + 4) = make_float4(acc[4], acc[5], acc[6], acc[7]);
}

// ---------------- fused WaveNet layer: weights in VGPRs, 4 tiles/block ----------------
// LDS map (bytes):
//   [0,     17408)  zT  64 rows x 272B (K-interleaved pairs, XOR-swizzled) | skb overlay (2x32x68 f32)
//   [17408, 26112)  cur32 32 x 68 f32
//   [26112, 59904)  gT  64 rows x 528B (K=256 halves + pad, gT-perm cols)
__global__ __launch_bounds__(256, 2) void layer_k(const float* __restrict__ resIn,
                                                  float* __restrict__ resOut,
                                                  const half_t* __restrict__ WaL,
                                                  const half_t* __restrict__ WrL, int d) {
  __shared__ __align__(16) char sm[59904];
  const int ZT_OFF = 0, CUR_OFF = 17408, GT_OFF = 26112, SKB_OFF = 0;
  int tid = threadIdx.x;
  int wave = tid >> 6, lane = tid & 63;
  int l31 = lane & 31, lhi = lane >> 5;
  int mh = wave & 1, nh = wave >> 1;   // GEMM1 roles; GEMM2: nh2 = mh, kh = nh

  // ---- persistent A-fragments from global (L2-hot) ----
  halfx8 a1h0[4], a1l0[4], a1h1[4], a1l1[4];
  {
    const half_t* wa = WaL + (mh * 64 + l31) * 128 + lhi * 8;
#pragma unroll
    for (int j = 0; j < 4; ++j) {
      a1h0[j] = *(const halfx8*)(wa + j * 16);
      a1l0[j] = *(const halfx8*)(wa + 64 + j * 16);
      a1h1[j] = *(const halfx8*)(wa + 32 * 128 + j * 16);
      a1l1[j] = *(const halfx8*)(wa + 32 * 128 + 64 + j * 16);
    }
  }
  halfx8 a2[12];
  {
    const half_t* wr = WrL + l31 * 256 + lhi * 8;
    if (nh == 0) {
#pragma unroll
      for (int j = 0; j < 8; ++j) a2[j] = *(const halfx8*)(wr + j * 16);
#pragma unroll
      for (int j = 8; j < 12; ++j) a2[j] = a2[j - 8];
    } else {
#pragma unroll
      for (int j = 0; j < 4; ++j) a2[j] = *(const halfx8*)(wr + 64 + j * 16);
#pragma unroll
      for (int j = 0; j < 8; ++j) a2[4 + j] = *(const halfx8*)(wr + 128 + j * 16);
    }
  }

  for (int ti = 0; ti < 4; ++ti) {
    int tile = blockIdx.x + ti * LGRID;
    int b = tile / NTILE;
    int t0 = (tile - b * NTILE) * TT;

    // ---- stage: cur32 f32 + zT fp16-split pairs ----
    {
      int c = tid >> 3, tw = (tid & 7) * 8;
      const float* rip = resIn + ((size_t)b * 32 + c) * T_LEN;
      float cv[8], pv[8];
      *(float4*)cv       = *(const float4*)(rip + t0 + tw);
      *(float4*)(cv + 4) = *(const float4*)(rip + t0 + tw + 4);
      int tp = t0 + tw - d;
      if (tp >= 0 && (d & 3) == 0) {
        *(float4*)pv       = *(const float4*)(rip + tp);
        *(float4*)(pv + 4) = *(const float4*)(rip + tp + 4);
      } else {
#pragma unroll
        for (int j = 0; j < 8; ++j) {
          int q = tp + j;
          pv[j] = (q >= 0) ? rip[q] : 0.f;
        }
      }
      float* cw = (float*)(sm + CUR_OFF) + c * 68 + tw;
      *(float4*)cw       = *(const float4*)cv;
      *(float4*)(cw + 4) = *(const float4*)(cv + 4);
#pragma unroll
      for (int j = 0; j < 8; ++j) {
        int t = tw + j;
        int sw = ((t >> 3) & 3) << 5;
        char* zrow = sm + ZT_OFF + t * 272;
        half_t p0 = (half_t)pv[j];
        half_t c0 = (half_t)cv[j];
        float pl = (pv[j] - (float)p0) * 2048.f;
        float cl = (cv[j] - (float)c0) * 2048.f;
        *(uint32*)(zrow + ((c * 4) ^ sw))       = packpair(pv[j], cv[j]);
        *(uint32*)(zrow + ((c * 4 + 128) ^ sw)) = packpair(pl, cl);
      }
    }
    __syncthreads();

    // ---- GEMM1: h[128,64] = Wa @ z (A in regs, B from zT) ----
    halfx8 gh0a, gh0b, gl0a, gl0b, gh1a, gh1b, gl1a, gl1b;
    {
      int colt = nh * 32 + l31;
      int sw = ((colt >> 3) & 3) << 5;
      const char* zr = sm + ZT_OFF + colt * 272;
      f32x16 hi0{}, hi1{}, lo0{}, lo1{};
#pragma unroll
      for (int ks = 0; ks < 12; ++ks) {
        int brow = (ks < 4) ? ks * 16 : ((ks < 8) ? (ks & 3) * 16 + 64 : (ks & 3) * 16);
        halfx8 bf = *(const halfx8*)(zr + ((brow * 2 + lhi * 16) ^ sw));
        if (ks < 4) {
          hi0 = MFMA(a1h0[ks], bf, hi0);
          hi1 = MFMA(a1h1[ks], bf, hi1);
        } else if (ks < 8) {
          lo0 = MFMA(a1h0[ks & 3], bf, lo0);
          lo1 = MFMA(a1h1[ks & 3], bf, lo1);
        } else {
          lo0 = MFMA(a1l0[ks & 3], bf, lo0);
          lo1 = MFMA(a1l1[ks & 3], bf, lo1);
        }
      }
#pragma unroll
      for (int r = 0; r < 16; ++r) {
        float ha = hi0[r] + lo0[r] * (1.f / 2048.f);
        float hb = hi1[r] + lo1[r] * (1.f / 2048.f);
        ha = fmaxf(ha, -30.f);
        hb = fmaxf(hb, -30.f);
        float ea = __expf(-ha), eb = __expf(-hb);
        float ga = (1.f - ea) * __builtin_amdgcn_rcpf(1.f + ea * ea);
        float gb = (1.f - eb) * __builtin_amdgcn_rcpf(1.f + eb * eb);
        half_t ga0 = (half_t)ga;
        half_t gb0 = (half_t)gb;
        half_t ga1 = (half_t)((ga - (float)ga0) * 2048.f);
        half_t gb1 = (half_t)((gb - (float)gb0) * 2048.f);
        if (r < 8) {
          gh0a[r] = ga0; gl0a[r] = ga1; gh1a[r] = gb0; gl1a[r] = gb1;
        } else {
          gh0b[r - 8] = ga0; gl0b[r - 8] = ga1; gh1b[r - 8] = gb0; gl1b[r - 8] = gb1;
        }
      }
      // gT write: K-col = mh*64 + tile*32 + lhi*16 + r (perm matches Wr repack)
      char* gr = sm + GT_OFF + colt * 528 + mh * 128 + lhi * 32;
      *(halfx8*)(gr)            = gh0a;
      *(halfx8*)(gr + 16)       = gh0b;
      *(halfx8*)(gr + 64)       = gh1a;
      *(halfx8*)(gr + 64 + 16)  = gh1b;
      *(halfx8*)(gr + 256)      = gl0a;
      *(halfx8*)(gr + 256 + 16) = gl0b;
      *(halfx8*)(gr + 320)      = gl1a;
      *(halfx8*)(gr + 320 + 16) = gl1b;
    }
    __syncthreads();

    // ---- GEMM2: skip[32,64] = Wr @ g (A in regs, B from gT) ----
    {
      int kh = nh;
      int colt2 = mh * 32 + l31;
      const char* g2 = sm + GT_OFF + colt2 * 528 + lhi * 16;
      f32x16 shi{}, slo{};
      if (kh == 0) {
#pragma unroll
        for (int ks = 0; ks < 12; ++ks) {
          int brow = (ks < 8) ? ks * 16 : (ks - 8) * 16 + 128;
          halfx8 bf = *(const halfx8*)(g2 + brow * 2);
          if (ks < 8) shi = MFMA(a2[ks], bf, shi);
          else        slo = MFMA(a2[ks], bf, slo);
        }
      } else {
#pragma unroll
        for (int ks = 0; ks < 12; ++ks) {
          int brow = (ks < 4) ? (ks + 4) * 16 + 128 : (ks - 4) * 16;
          halfx8 bf = *(const halfx8*)(g2 + brow * 2);
          slo = MFMA(a2[ks], bf, slo);
        }
      }
      // skb partials (overlay zT; all waves past GEMM1 reads due to gT barrier)
      float* skb = (float*)(sm + SKB_OFF) + kh * 32 * 68;
#pragma unroll
      for (int r = 0; r < 16; ++r) {
        int row = (r & 3) + 8 * (r >> 2) + 4 * lhi;
        skb[row * 68 + colt2] = shi[r] + slo[r] * (1.f / 2048.f);
      }
    }
    __syncthreads();

    // ---- writeout: resOut = cur + skip ----
    {
      int c = tid >> 3, tw = (tid & 7) * 8;
      const float* s0 = (const float*)(sm + SKB_OFF) + c * 68 + tw;
      const float* s1 = s0 + 32 * 68;
      const float* cu = (const float*)(sm + CUR_OFF) + c * 68 + tw;
      size_t base = ((size_t)b * 32 + c) * T_LEN + t0 + tw;
#pragma unroll
      for (int v = 0; v < 8; v += 4) {
        float4 sa = *(const float4*)(s0 + v);
        float4 sb = *(const float4*)(s1 + v);
        float4 cv = *(const float4*)(cu + v);
        float4 o;
        o.x = cv.x + sa.x + sb.x;
        o.y = cv.y + sa.y + sb.y;
        o.z = cv.z + sa.z + sb.z;
        o.w = cv.w + sa.w + sb.w;
        *(float4*)(resOut + base + v) = o;
      }
    }
    __syncthreads();
  }
}

// ---------------- end: relu(resF-res0) -> relu(We1@.) -> We2@. , MFMA split-2 ----------------
__global__ __launch_bounds__(512) void end_k(const float* __restrict__ resF,
                                             const float* __restrict__ res0,
                                             const half_t* __restrict__ We1S,
                                             const half_t* __restrict__ We2S,
                                             float* __restrict__ out) {
  __shared__ __align__(16) char sm[75776];
  const int H2T_OFF = 0, H1F_OFF = 0, H1T_OFF = 66560;
  int tid = threadIdx.x;
  int b = blockIdx.x / NTILE;
  int t0 = (blockIdx.x % NTILE) * TT;

  {
    int c = tid >> 4, tt4 = (tid & 15) * 4;
    size_t base = ((size_t)b * 32 + c) * T_LEN + t0 + tt4;
    float4 f = *(const float4*)(resF + base);
    float4 z = *(const float4*)(res0 + base);
    float* h1 = (float*)(sm + H1F_OFF) + c * 68 + tt4;
    h1[0] = fmaxf(f.x - z.x, 0.f);
    h1[1] = fmaxf(f.y - z.y, 0.f);
    h1[2] = fmaxf(f.z - z.z, 0.f);
    h1[3] = fmaxf(f.w - z.w, 0.f);
  }
  __syncthreads();
  {
    int t = tid & 63, cg = tid >> 6;
    const float* h1 = (const float*)(sm + H1F_OFF);
    halfx4 hi, lo;
#pragma unroll
    for (int j = 0; j < 4; ++j) {
      float v = h1[(cg * 4 + j) * 68 + t];
      half_t h = (half_t)v;
      hi[j] = h;
      lo[j] = (half_t)((v - (float)h) * 2048.f);
    }
    half_t* h1t = (half_t*)(sm + H1T_OFF) + t * 72;
    *(halfx4*)(h1t + cg * 4)      = hi;
    *(halfx4*)(h1t + 32 + cg * 4) = lo;
  }
  __syncthreads();

  int wave = tid >> 6, lane = tid & 63;
  int l31 = lane & 31, lhi = lane >> 5;

  f32x16 aHi0{}, aHi1{}, aLo0{}, aLo1{};
  {
    const char* h1t = sm + H1T_OFF;
    const half_t* wp = We1S + (wave * 32 + l31) * 64;
#pragma unroll
    for (int ks = 0; ks < 2; ++ks) {
      halfx8 hiA = *(const halfx8*)(wp + ks * 16 + lhi * 8);
      halfx8 loA = *(const halfx8*)(wp + 32 + ks * 16 + lhi * 8);
      const char* br0 = h1t + l31 * 144;
      const char* br1 = h1t + (32 + l31) * 144;
      halfx8 hiB0 = *(const halfx8*)(br0 + (ks * 16 + lhi * 8) * 2);
      halfx8 loB0 = *(const halfx8*)(br0 + (32 + ks * 16 + lhi * 8) * 2);
      halfx8 hiB1 = *(const halfx8*)(br1 + (ks * 16 + lhi * 8) * 2);
      halfx8 loB1 = *(const halfx8*)(br1 + (32 + ks * 16 + lhi * 8) * 2);
      aHi0 = MFMA(hiA, hiB0, aHi0);
      aLo0 = MFMA(hiA, loB0, aLo0);
      aLo0 = MFMA(loA, hiB0, aLo0);
      aHi1 = MFMA(hiA, hiB1, aHi1);
      aLo1 = MFMA(hiA, loB1, aLo1);
      aLo1 = MFMA(loA, hiB1, aLo1);
    }
  }
  {
#pragma unroll
    for (int n = 0; n < 2; ++n) {
      const f32x16& aH = n ? aHi1 : aHi0;
      const f32x16& aL = n ? aLo1 : aLo0;
      int t = n * 32 + l31;
      half_t* row = (half_t*)(sm + H2T_OFF) + t * 520;
#pragma unroll
      for (int g = 0; g < 4; ++g) {
        halfx4 hi, lo;
#pragma unroll
        for (int j = 0; j < 4; ++j) {
          int r = g * 4 + j;
          float v = aH[r] + aL[r] * (1.f / 2048.f);
          v = fmaxf(v, 0.f);
          half_t h = (half_t)v;
          hi[j] = h;
          lo[j] = (half_t)((v - (float)h) * 2048.f);
        }
        int col = wave * 32 + g * 8 + lhi * 4;
        *(halfx4*)(row + col)       = hi;
        *(halfx4*)(row + 256 + col) = lo;
      }
    }
  }
  __syncthreads();

  f32x16 bHi0{}, bHi1{}, bLo0{}, bLo1{};
  {
    const half_t* wp = We2S + (size_t)(wave * 32 + l31) * 512;
    const char* h2t = sm + H2T_OFF;
#pragma unroll 2
    for (int ks = 0; ks < 16; ++ks) {
      halfx8 hiA = *(const halfx8*)(wp + ks * 16 + lhi * 8);
      halfx8 loA = *(const halfx8*)(wp + 256 + ks * 16 + lhi * 8);
      const char* br0 = h2t + l31 * 1040;
      const char* br1 = h2t + (32 + l31) * 1040;
      halfx8 hiB0 = *(const halfx8*)(br0 + (ks * 16 + lhi * 8) * 2);
      halfx8 loB0 = *(const halfx8*)(br0 + (256 + ks * 16 + lhi * 8) * 2);
      halfx8 hiB1 = *(const halfx8*)(br1 + (ks * 16 + lhi * 8) * 2);
      halfx8 loB1 = *(const halfx8*)(br1 + (256 + ks * 16 + lhi * 8) * 2);
      bHi0 = MFMA(hiA, hiB0, bHi0);
      bLo0 = MFMA(hiA, loB0, bLo0);
      bLo0 = MFMA(loA, hiB0, bLo0);
      bHi1 = MFMA(hiA, hiB1, bHi1);
      bLo1 = MFMA(hiA, loB1, bLo1);
      bLo1 = MFMA(loA, hiB1, bLo1);
    }
  }
  {
#pragma unroll
    for (int n = 0; n < 2; ++n) {
      const f32x16& bH = n ? bHi1 : bHi0;
      const f32x16& bL = n ? bLo1 : bLo0;
      int t = t0 + n * 32 + l31;
#pragma unroll
      for (int r = 0; r < 16; ++r) {
        int o = wave * 32 + (r & 3) + 8 * (r >> 2) + 4 * lhi;
        out[((size_t)b * 256 + o) * T_LEN + t] = bH[r] + bL[r] * (1.f / 2048.f);
      }
    }
  }
}

extern "C" void kernel_launch(void* const* d_in, const int* in_sizes, int n_in,
                              void* d_out, int out_size, void* d_ws, size_t ws_size,
                              hipStream_t stream) {
  const float* x   = (const float*)d_in[0];
  const float* Wst = (const float*)d_in[1];
  const float* Wd  = (const float*)d_in[2];
  const float* Wr  = (const float*)d_in[3];
  const float* We1 = (const float*)d_in[4];
  const float* We2 = (const float*)d_in[5];
  float* out = (float*)d_out;
  float* ws = (float*)d_ws;

  float* resA = ws;                        // start output (skips = resF - resA)
  float* resB = resA + N_RES;
  float* resC = resB + N_RES;
  half_t* WaG  = (half_t*)(resC + N_RES);  // 40*16384
  half_t* WrG  = WaG + 40 * 16384;         // 40*8192
  float*  WsT  = (float*)(WrG + 40 * 8192);
  half_t* We1S = (half_t*)(WsT + 8192);    // 16384
  half_t* We2S = We1S + 16384;             // 131072

  repack_k<<<2560, 256, 0, stream>>>(Wd, Wr, Wst, We1, We2, WaG, WrG, WsT, We1S, We2S);
  start_k<<<NBLK, 256, 0, stream>>>(x, WsT, resA);

  const float* rin = resA;
  for (int l = 0; l < 40; ++l) {
    float* rout = (l & 1) ? resC : resB;
    layer_k<<<LGRID, 256, 0, stream>>>(rin, rout, WaG + l * 16384, WrG + l * 8192,
                                       1 << (l % 10));
    rin = rout;
  }
  end_k<<<NBLK, 512, 0, stream>>>(rin, resA, We1S, We2S, out);
}